// Round 10
// baseline (342.411 us; speedup 1.0000x reference)
//
#include <hip/hip_runtime.h>

#define INPUT 32
#define HIDDEN 64
#define BATCH 4096
#define SEQ 256

typedef __attribute__((ext_vector_type(8))) short bf16x8;   // 8 bf16 (4 VGPRs)
typedef __attribute__((ext_vector_type(4))) float floatx4;  // 4 fp32

#define MFMA(a, b, c) __builtin_amdgcn_mfma_f32_16x16x32_bf16((a), (b), (c), 0, 0, 0)

// RNE f32->bf16 (setup-only, for static weights).
__device__ __forceinline__ unsigned short f2bf(float f) {
    unsigned u = __float_as_uint(f);
    u += 0x7fffu + ((u >> 16) & 1u);
    return (unsigned short)(u >> 16);
}
__device__ __forceinline__ float bf2f(unsigned short b) {
    return __uint_as_float(((unsigned)b) << 16);
}
__device__ __forceinline__ void split8(const float f[8], bf16x8& hi, bf16x8& lo) {
#pragma unroll
    for (int j = 0; j < 8; ++j) {
        unsigned short h = f2bf(f[j]);
        hi[j] = (short)h;
        lo[j] = (short)f2bf(f[j] - bf2f(h));
    }
}

// Truncation split of a pair -> packed hi/lo words (6 VALU).
__device__ __forceinline__ void packpair(float f0, float f1, unsigned& hw, unsigned& lw) {
    unsigned b0 = __float_as_uint(f0), b1 = __float_as_uint(f1);
    float h0 = __uint_as_float(b0 & 0xffff0000u);
    float h1 = __uint_as_float(b1 & 0xffff0000u);
    float l0 = f0 - h0, l1 = f1 - h1;
    hw = __builtin_amdgcn_perm(b1, b0, 0x07060302u);
    lw = __builtin_amdgcn_perm(__float_as_uint(l1), __float_as_uint(l0), 0x07060302u);
}

union FragU { bf16x8 v; unsigned u[4]; };

// Round-9 diagnosis: of 1515 cyc/step, ~1000 were multi-wave taxes (shared
// LDS-pipe bursts, write->lgkm->barrier->read turnaround, 4-wave barrier skew
// x256 steps). MFMA was only 9% busy -- the N-split bought parallelism we
// don't need at a per-step sync price we can't afford.
//
// This version: ONE wave owns the whole 16-chain tile (all 64 hidden units,
// 4 u-tiles, 36 MFMA/step). 256 independent waves on 256 CUs. NO barriers:
// same-wave LDS ops are in-order (empirically validated by round-5's
// barrier-free LDS round-trip passing on this exact problem). Single LDS
// buffer is safe: write data depends on read results, so reads have
// completed before writes issue. Kept from r6-r9: writer-side hi/lo split
// (state B-frag = 4 ds_read_b128, shared across u-tiles), verified swizzle,
// 4-slot x pipeline, ih-offload.
//
// Layouts (verified r5-r9): C/D row(m)=4qd+r, col(n)=ln. A: m=ln, k=8qd+j.
//   B: n=ln, k=8qd+j (+32kt). Here A=W rows (u=16nt+ln per tile nt),
//   B=state G[k=hidden][n=batch col], C rows = hidden u=16nt+4qd+r.
// G in LDS (u16): pl*1024 + kt*512 + ln*32 + slot*8 + j, slot=(qd+(ln>>1))&3.
__global__ __launch_bounds__(64, 1) void rnn_sw_kernel(
    const float* __restrict__ x,     // [B, T, 32]
    const float* __restrict__ W_ih,  // [64, 32]
    const float* __restrict__ W_hh,  // [64, 64]
    const float* __restrict__ b_ih,  // [64]
    const float* __restrict__ b_hh,  // [64]
    const float* __restrict__ W_fc,  // [1, 64]
    const float* __restrict__ b_fc,  // [1]
    float* __restrict__ out)         // [B, 1]
{
    const int lane = threadIdx.x;    // block = exactly one wave
    const int ln   = lane & 15;
    const int qd   = lane >> 4;
    const int b0   = blockIdx.x * 16;

    __shared__ __align__(16) unsigned short Gs[2048];  // 4 KB, single buffer

    // h_{-1} = 0 (same-wave in-order LDS: no barrier needed).
    {
        unsigned* z = (unsigned*)Gs;
#pragma unroll
        for (int i = 0; i < 16; ++i) z[lane + i * 64] = 0u;
    }

    // ---- Static A-operand weights for 4 u-tiles, RNE hi/lo split ----
    bf16x8 WihH[4], WihL[4], WhhH[4][2], WhhL[4][2];
    floatx4 bbv[4];
#pragma unroll
    for (int nt = 0; nt < 4; ++nt) {
        const int mrow = nt * 16 + ln;
        float f[8];
        const float* ri = W_ih + mrow * INPUT + qd * 8;
        *(float4*)&f[0] = *(const float4*)ri;
        *(float4*)&f[4] = *(const float4*)(ri + 4);
        split8(f, WihH[nt], WihL[nt]);
        const float* rh = W_hh + mrow * HIDDEN + qd * 8;
#pragma unroll
        for (int kt = 0; kt < 2; ++kt) {
            *(float4*)&f[0] = *(const float4*)(rh + kt * 32);
            *(float4*)&f[4] = *(const float4*)(rh + kt * 32 + 4);
            split8(f, WhhH[nt][kt], WhhL[nt][kt]);
        }
        const int u0 = nt * 16 + qd * 4;   // bias rows for this lane's C regs
        float4 bi = *(const float4*)(b_ih + u0);
        float4 bh = *(const float4*)(b_hh + u0);
        bbv[nt][0] = bi.x + bh.x; bbv[nt][1] = bi.y + bh.y;
        bbv[nt][2] = bi.z + bh.z; bbv[nt][3] = bi.w + bh.w;
    }

    const int rbase = ln * 32 + ((qd + (ln >> 1)) & 3) * 8;
    int woff[4][2];
#pragma unroll
    for (int nt = 0; nt < 4; ++nt)
#pragma unroll
        for (int p = 0; p < 2; ++p) {
            const int u = nt * 16 + qd * 4 + 2 * p;
            woff[nt][p] = (u >> 5) * 512 + ln * 32 + ((((u >> 3) & 3) + (ln >> 1)) & 3) * 8 + (u & 7);
        }

    const float* xp = x + (size_t)(b0 + ln) * (SEQ * INPUT) + qd * 8;

    // 4-slot circular x prefetch (slot s holds x[t], t === s mod 4).
    float4 xa[4], xb[4];
#pragma unroll
    for (int i = 0; i < 4; ++i) {
        xa[i] = *(const float4*)(xp + i * INPUT);
        xb[i] = *(const float4*)(xp + i * INPUT + 4);
    }

    // ih-projection for t=0.
    floatx4 ihacc[4];
    {
        FragU xH, xL;
        packpair(xa[0].x, xa[0].y, xH.u[0], xL.u[0]);
        packpair(xa[0].z, xa[0].w, xH.u[1], xL.u[1]);
        packpair(xb[0].x, xb[0].y, xH.u[2], xL.u[2]);
        packpair(xb[0].z, xb[0].w, xH.u[3], xL.u[3]);
#pragma unroll
        for (int nt = 0; nt < 4; ++nt) {
            floatx4 a = bbv[nt];
            a = MFMA(WihH[nt], xH.v, a);
            a = MFMA(WihH[nt], xL.v, a);
            a = MFMA(WihL[nt], xH.v, a);
            ihacc[nt] = a;
        }
    }

    float hv[4][4];

#pragma unroll 1
    for (int tb = 0; tb < SEQ; tb += 4) {
#pragma unroll
        for (int s = 0; s < 4; ++s) {
            const int t = tb + s;
            // Refill slot s with x[t+4] (3 steps of slack before use).
            const int tn = (t + 4 < SEQ) ? t + 4 : SEQ - 1;
            xa[s] = *(const float4*)(xp + tn * INPUT);
            xb[s] = *(const float4*)(xp + tn * INPUT + 4);

            // State B-frags (shared by all 4 u-tiles): 4 ds_read_b128.
            const unsigned short* Hr = Gs + rbase;
            bf16x8 gH0 = *(const bf16x8*)(Hr);          // pl0 kt0
            bf16x8 gH1 = *(const bf16x8*)(Hr + 512);    // pl0 kt1
            bf16x8 gL0 = *(const bf16x8*)(Hr + 1024);   // pl1 kt0
            bf16x8 gL1 = *(const bf16x8*)(Hr + 1536);   // pl1 kt1

            // Off-path (fills ds_read latency): ih-projection for t+1.
            const float4 na = xa[(s + 1) & 3], nb = xb[(s + 1) & 3];
            FragU nxH, nxL;
            packpair(na.x, na.y, nxH.u[0], nxL.u[0]);
            packpair(na.z, na.w, nxH.u[1], nxL.u[1]);
            packpair(nb.x, nb.y, nxH.u[2], nxL.u[2]);
            packpair(nb.z, nb.w, nxH.u[3], nxL.u[3]);
            floatx4 ihn[4];
#pragma unroll
            for (int nt = 0; nt < 4; ++nt) {
                floatx4 a = bbv[nt];
                a = MFMA(WihH[nt], nxH.v, a);
                a = MFMA(WihH[nt], nxL.v, a);
                a = MFMA(WihL[nt], nxH.v, a);
                ihn[nt] = a;
            }

            // hh: 8 independent depth-3 chains (2 per u-tile) -> issue-bound.
#pragma unroll
            for (int nt = 0; nt < 4; ++nt) {
                floatx4 a = ihacc[nt];
                a = MFMA(WhhH[nt][0], gH0, a);
                a = MFMA(WhhH[nt][0], gL0, a);
                a = MFMA(WhhL[nt][0], gH0, a);
                floatx4 a2 = {0.f, 0.f, 0.f, 0.f};
                a2 = MFMA(WhhH[nt][1], gH1, a2);
                a2 = MFMA(WhhH[nt][1], gL1, a2);
                a2 = MFMA(WhhL[nt][1], gH1, a2);
#pragma unroll
                for (int r = 0; r < 4; ++r) {
                    float p = a[r] + a2[r];
                    float e = __expf(2.0f * p);
                    hv[nt][r] = 1.0f - 2.0f * __builtin_amdgcn_rcpf(e + 1.0f);
                }
            }

            // Writer-side split back into the (single) G buffer.
            // Safe: write data depends on the reads above, so reads already
            // completed; same-wave DS ops process in order.
#pragma unroll
            for (int nt = 0; nt < 4; ++nt)
#pragma unroll
                for (int p = 0; p < 2; ++p) {
                    unsigned hw, lw;
                    packpair(hv[nt][2 * p], hv[nt][2 * p + 1], hw, lw);
                    *(unsigned*)(Gs + woff[nt][p])        = hw;   // hi plane
                    *(unsigned*)(Gs + 1024 + woff[nt][p]) = lw;   // lo plane
                }

#pragma unroll
            for (int nt = 0; nt < 4; ++nt) ihacc[nt] = ihn[nt];
        }
    }

    // ---- Head: out[b0+ln] = sum_u W_fc[u] * G[u][ln] + b_fc ----
    float acc = 0.0f;
#pragma unroll
    for (int nt = 0; nt < 4; ++nt) {
        float4 wf = *(const float4*)(W_fc + nt * 16 + qd * 4);
        acc = fmaf(wf.x, hv[nt][0], acc);
        acc = fmaf(wf.y, hv[nt][1], acc);
        acc = fmaf(wf.z, hv[nt][2], acc);
        acc = fmaf(wf.w, hv[nt][3], acc);
    }
    acc += __shfl_xor(acc, 16, 64);   // combine the 4 qd lanes of column ln
    acc += __shfl_xor(acc, 32, 64);
    if (lane < 16) out[b0 + lane] = acc + b_fc[0];
}

extern "C" void kernel_launch(void* const* d_in, const int* in_sizes, int n_in,
                              void* d_out, int out_size, void* d_ws, size_t ws_size,
                              hipStream_t stream) {
    const float* x    = (const float*)d_in[0];
    const float* W_ih = (const float*)d_in[1];
    const float* W_hh = (const float*)d_in[2];
    const float* b_ih = (const float*)d_in[3];
    const float* b_hh = (const float*)d_in[4];
    const float* W_fc = (const float*)d_in[5];
    const float* b_fc = (const float*)d_in[6];
    float* out = (float*)d_out;

    // 256 tiles of 16 chains; ONE wave per tile, one tile per CU. No barriers.
    rnn_sw_kernel<<<dim3(BATCH / 16), dim3(64), 0, stream>>>(
        x, W_ih, W_hh, b_ih, b_hh, W_fc, b_fc, out);
}

// Round 11
// 311.615 us; speedup vs baseline: 1.0988x; 1.0988x over previous
//
#include <hip/hip_runtime.h>

#define INPUT 32
#define HIDDEN 64
#define BATCH 4096
#define SEQ 256

typedef __attribute__((ext_vector_type(8))) short bf16x8;   // 8 bf16 (4 VGPRs)
typedef __attribute__((ext_vector_type(4))) float floatx4;  // 4 fp32

#define MFMA(a, b, c) __builtin_amdgcn_mfma_f32_16x16x32_bf16((a), (b), (c), 0, 0, 0)

// RNE f32->bf16 scalar (setup-only, for static weights).
__device__ __forceinline__ unsigned short f2bf(float f) {
    unsigned u = __float_as_uint(f);
    u += 0x7fffu + ((u >> 16) & 1u);
    return (unsigned short)(u >> 16);
}
__device__ __forceinline__ float bf2f(unsigned short b) {
    return __uint_as_float(((unsigned)b) << 16);
}
__device__ __forceinline__ void split8(const float f[8], bf16x8& hi, bf16x8& lo) {
#pragma unroll
    for (int j = 0; j < 8; ++j) {
        unsigned short h = f2bf(f[j]);
        hi[j] = (short)h;
        lo[j] = (short)f2bf(f[j] - bf2f(h));
    }
}

// Truncation split of a pair -> packed hi/lo words (6 VALU). Used for x.
__device__ __forceinline__ void packpair(float f0, float f1, unsigned& hw, unsigned& lw) {
    unsigned b0 = __float_as_uint(f0), b1 = __float_as_uint(f1);
    float h0 = __uint_as_float(b0 & 0xffff0000u);
    float h1 = __uint_as_float(b1 & 0xffff0000u);
    float l0 = f0 - h0, l1 = f1 - h1;
    hw = __builtin_amdgcn_perm(b1, b0, 0x07060302u);
    lw = __builtin_amdgcn_perm(__float_as_uint(l1), __float_as_uint(l0), 0x07060302u);
}

// RNE pack of a pair (state h: accuracy matters, it's the recurrent signal).
__device__ __forceinline__ unsigned pack_rne(float f0, float f1) {
#if __has_builtin(__builtin_amdgcn_cvt_pk_bf16_f32)
    auto r = __builtin_amdgcn_cvt_pk_bf16_f32(f0, f1);
    unsigned u;
    __builtin_memcpy(&u, &r, 4);
    return u;
#else
    unsigned r0 = __float_as_uint(f0);
    r0 += 0x7fffu + ((r0 >> 16) & 1u);
    unsigned r1 = __float_as_uint(f1);
    r1 += 0x7fffu + ((r1 >> 16) & 1u);
    return __builtin_amdgcn_perm(r1, r0, 0x07060302u);
#endif
}

union FragU { bf16x8 v; unsigned u[4]; };

// Round-10 calibration: single-wave step = 1890 cyc, of which issue is only
// 430 (VALU 289 + MFMA 142) -> 77% dependency stall on the loop-carried
// chain: 16 ds_write -> FIFO -> 4 ds_read -> depth-3 MFMA -> 16 tanh ->
// 8 packs -> writes. TLP is capped (256 chains, 1024 SIMDs), so this round
// SHORTENS THE CHAIN:
//  - state kept hi-plane-only (RNE bf16): DS ops 20 -> 10, MFMA depth 3 -> 2.
//    Weight-lo correction (WhhL x gH) kept in a parallel accumulator; x
//    hi/lo kept. New error = state quantization only (~+1.5e-3 settled).
//  - G reads issued at iteration END (straight after writes) so read
//    latency overlaps next step's off-path x-pack / ih-MFMAs.
// Layouts (verified r5-r10): C/D row(m)=4qd+r, col(n)=ln. A: m=ln, k=8qd+j.
//   B: n=ln, k=8qd+j (+32kt). A=W rows, B=state G[k=u][n=batch].
// G in LDS (u16): kt*512 + ln*32 + slot*8 + j, slot=(qd+(ln>>1))&3
//   (reads <=2-way per phase = free; writes <=4-way, ~13 cyc, acceptable).
__global__ __launch_bounds__(64, 1) void rnn_sw2_kernel(
    const float* __restrict__ x,     // [B, T, 32]
    const float* __restrict__ W_ih,  // [64, 32]
    const float* __restrict__ W_hh,  // [64, 64]
    const float* __restrict__ b_ih,  // [64]
    const float* __restrict__ b_hh,  // [64]
    const float* __restrict__ W_fc,  // [1, 64]
    const float* __restrict__ b_fc,  // [1]
    float* __restrict__ out)         // [B, 1]
{
    const int lane = threadIdx.x;    // block = exactly one wave
    const int ln   = lane & 15;
    const int qd   = lane >> 4;
    const int b0   = blockIdx.x * 16;

    __shared__ __align__(16) unsigned short Gs[1024];  // 2 KB: hi plane only

    // h_{-1} = 0 (same-wave in-order LDS: no barrier needed).
    {
        unsigned* z = (unsigned*)Gs;
#pragma unroll
        for (int i = 0; i < 8; ++i) z[lane + i * 64] = 0u;
    }

    // ---- Static A-operand weights for 4 u-tiles, RNE hi/lo split ----
    bf16x8 WihH[4], WihL[4], WhhH[4][2], WhhL[4][2];
    floatx4 bbv[4];
#pragma unroll
    for (int nt = 0; nt < 4; ++nt) {
        const int mrow = nt * 16 + ln;
        float f[8];
        const float* ri = W_ih + mrow * INPUT + qd * 8;
        *(float4*)&f[0] = *(const float4*)ri;
        *(float4*)&f[4] = *(const float4*)(ri + 4);
        split8(f, WihH[nt], WihL[nt]);
        const float* rh = W_hh + mrow * HIDDEN + qd * 8;
#pragma unroll
        for (int kt = 0; kt < 2; ++kt) {
            *(float4*)&f[0] = *(const float4*)(rh + kt * 32);
            *(float4*)&f[4] = *(const float4*)(rh + kt * 32 + 4);
            split8(f, WhhH[nt][kt], WhhL[nt][kt]);
        }
        const int u0 = nt * 16 + qd * 4;
        float4 bi = *(const float4*)(b_ih + u0);
        float4 bh = *(const float4*)(b_hh + u0);
        bbv[nt][0] = bi.x + bh.x; bbv[nt][1] = bi.y + bh.y;
        bbv[nt][2] = bi.z + bh.z; bbv[nt][3] = bi.w + bh.w;
    }

    const int rbase = ln * 32 + ((qd + (ln >> 1)) & 3) * 8;
    int woff[4][2];
#pragma unroll
    for (int nt = 0; nt < 4; ++nt)
#pragma unroll
        for (int p = 0; p < 2; ++p) {
            const int u = nt * 16 + qd * 4 + 2 * p;
            woff[nt][p] = (u >> 5) * 512 + ln * 32 + ((((u >> 3) & 3) + (ln >> 1)) & 3) * 8 + (u & 7);
        }

    const float* xp = x + (size_t)(b0 + ln) * (SEQ * INPUT) + qd * 8;

    // 4-slot circular x prefetch (slot s holds x[t], t === s mod 4).
    float4 xa[4], xb[4];
#pragma unroll
    for (int i = 0; i < 4; ++i) {
        xa[i] = *(const float4*)(xp + i * INPUT);
        xb[i] = *(const float4*)(xp + i * INPUT + 4);
    }

    // ih-projection for t=0 (bias seeded via the MFMA C operand).
    floatx4 ihacc[4];
    {
        FragU xH, xL;
        packpair(xa[0].x, xa[0].y, xH.u[0], xL.u[0]);
        packpair(xa[0].z, xa[0].w, xH.u[1], xL.u[1]);
        packpair(xb[0].x, xb[0].y, xH.u[2], xL.u[2]);
        packpair(xb[0].z, xb[0].w, xH.u[3], xL.u[3]);
#pragma unroll
        for (int nt = 0; nt < 4; ++nt) {
            floatx4 a = MFMA(WihH[nt], xH.v, bbv[nt]);
            a = MFMA(WihH[nt], xL.v, a);
            a = MFMA(WihL[nt], xH.v, a);
            ihacc[nt] = a;
        }
    }

    // Preload G frags for t=0 (reads queued after the zero-init writes).
    bf16x8 gH0 = *(const bf16x8*)(Gs + rbase);          // kt0
    bf16x8 gH1 = *(const bf16x8*)(Gs + rbase + 512);    // kt1

    float hv[4][4];

#pragma unroll 1
    for (int tb = 0; tb < SEQ; tb += 4) {
#pragma unroll
        for (int s = 0; s < 4; ++s) {
            const int t = tb + s;
            // Refill slot s with x[t+4] (3 steps of slack before use).
            const int tn = (t + 4 < SEQ) ? t + 4 : SEQ - 1;
            xa[s] = *(const float4*)(xp + tn * INPUT);
            xb[s] = *(const float4*)(xp + tn * INPUT + 4);

            // Off-path: ih-projection for t+1 (overlaps G read latency).
            const float4 na = xa[(s + 1) & 3], nb = xb[(s + 1) & 3];
            FragU nxH, nxL;
            packpair(na.x, na.y, nxH.u[0], nxL.u[0]);
            packpair(na.z, na.w, nxH.u[1], nxL.u[1]);
            packpair(nb.x, nb.y, nxH.u[2], nxL.u[2]);
            packpair(nb.z, nb.w, nxH.u[3], nxL.u[3]);
            floatx4 ihn[4];
#pragma unroll
            for (int nt = 0; nt < 4; ++nt) {
                floatx4 a = MFMA(WihH[nt], nxH.v, bbv[nt]);
                a = MFMA(WihH[nt], nxL.v, a);
                a = MFMA(WihL[nt], nxH.v, a);
                ihn[nt] = a;
            }

            // hh on the critical path: depth-2 main chain + parallel depth-2
            // weight-lo correction, per u-tile (16 MFMA total).
#pragma unroll
            for (int nt = 0; nt < 4; ++nt) {
                floatx4 a = MFMA(WhhH[nt][0], gH0, ihacc[nt]);
                a = MFMA(WhhH[nt][1], gH1, a);
                floatx4 c = {0.f, 0.f, 0.f, 0.f};
                c = MFMA(WhhL[nt][0], gH0, c);
                c = MFMA(WhhL[nt][1], gH1, c);
#pragma unroll
                for (int r = 0; r < 4; ++r) {
                    float p = a[r] + c[r];
                    float e = __expf(2.0f * p);
                    hv[nt][r] = 1.0f - 2.0f * __builtin_amdgcn_rcpf(e + 1.0f);
                }
            }

            // RNE-pack state and write hi plane: 8 ds_write_b32.
#pragma unroll
            for (int nt = 0; nt < 4; ++nt)
#pragma unroll
                for (int p = 0; p < 2; ++p)
                    *(unsigned*)(Gs + woff[nt][p]) =
                        pack_rne(hv[nt][2 * p], hv[nt][2 * p + 1]);

            // Read G for step t+1 now (FIFO after writes -> sees new state;
            // latency overlaps next iteration's off-path work).
            gH0 = *(const bf16x8*)(Gs + rbase);
            gH1 = *(const bf16x8*)(Gs + rbase + 512);

#pragma unroll
            for (int nt = 0; nt < 4; ++nt) ihacc[nt] = ihn[nt];
        }
    }

    // ---- Head: out[b0+ln] = sum_u W_fc[u] * h[u][ln] + b_fc ----
    float acc = 0.0f;
#pragma unroll
    for (int nt = 0; nt < 4; ++nt) {
        float4 wf = *(const float4*)(W_fc + nt * 16 + qd * 4);
        acc = fmaf(wf.x, hv[nt][0], acc);
        acc = fmaf(wf.y, hv[nt][1], acc);
        acc = fmaf(wf.z, hv[nt][2], acc);
        acc = fmaf(wf.w, hv[nt][3], acc);
    }
    acc += __shfl_xor(acc, 16, 64);   // combine the 4 qd lanes of column ln
    acc += __shfl_xor(acc, 32, 64);
    if (lane < 16) out[b0 + lane] = acc + b_fc[0];
}

extern "C" void kernel_launch(void* const* d_in, const int* in_sizes, int n_in,
                              void* d_out, int out_size, void* d_ws, size_t ws_size,
                              hipStream_t stream) {
    const float* x    = (const float*)d_in[0];
    const float* W_ih = (const float*)d_in[1];
    const float* W_hh = (const float*)d_in[2];
    const float* b_ih = (const float*)d_in[3];
    const float* b_hh = (const float*)d_in[4];
    const float* W_fc = (const float*)d_in[5];
    const float* b_fc = (const float*)d_in[6];
    float* out = (float*)d_out;

    // 256 tiles of 16 chains; ONE wave per tile, one tile per CU. No barriers.
    rnn_sw2_kernel<<<dim3(BATCH / 16), dim3(64), 0, stream>>>(
        x, W_ih, W_hh, b_ih, b_hh, W_fc, b_fc, out);
}

// Round 12
// 287.340 us; speedup vs baseline: 1.1917x; 1.0845x over previous
//
#include <hip/hip_runtime.h>

#define INPUT 32
#define HIDDEN 64
#define BATCH 4096
#define SEQ 256

typedef __attribute__((ext_vector_type(8))) short bf16x8;   // 8 bf16 (4 VGPRs)
typedef __attribute__((ext_vector_type(4))) float floatx4;  // 4 fp32

#define MFMA(a, b, c) __builtin_amdgcn_mfma_f32_16x16x32_bf16((a), (b), (c), 0, 0, 0)

// LDS-only barrier: wait LDS ops, leave global loads in flight.
#define LDS_BARRIER() asm volatile("s_waitcnt lgkmcnt(0)\n\ts_barrier" ::: "memory")

// RNE f32->bf16 scalar (setup-only).
__device__ __forceinline__ unsigned short f2bf(float f) {
    unsigned u = __float_as_uint(f);
    u += 0x7fffu + ((u >> 16) & 1u);
    return (unsigned short)(u >> 16);
}
__device__ __forceinline__ float bf2f(unsigned short b) {
    return __uint_as_float(((unsigned)b) << 16);
}
__device__ __forceinline__ void split8(const float f[8], bf16x8& hi, bf16x8& lo) {
#pragma unroll
    for (int j = 0; j < 8; ++j) {
        unsigned short h = f2bf(f[j]);
        hi[j] = (short)h;
        lo[j] = (short)f2bf(f[j] - bf2f(h));
    }
}

// Truncation split of a pair -> packed hi/lo words (6 VALU). Used for x.
__device__ __forceinline__ void packpair(float f0, float f1, unsigned& hw, unsigned& lw) {
    unsigned b0 = __float_as_uint(f0), b1 = __float_as_uint(f1);
    float h0 = __uint_as_float(b0 & 0xffff0000u);
    float h1 = __uint_as_float(b1 & 0xffff0000u);
    float l0 = f0 - h0, l1 = f1 - h1;
    hw = __builtin_amdgcn_perm(b1, b0, 0x07060302u);
    lw = __builtin_amdgcn_perm(__float_as_uint(l1), __float_as_uint(l0), 0x07060302u);
}

// RNE pack of a pair (recurrent state: accuracy matters).
__device__ __forceinline__ unsigned pack_rne(float f0, float f1) {
    unsigned r0 = __float_as_uint(f0);
    r0 += 0x7fffu + ((r0 >> 16) & 1u);
    unsigned r1 = __float_as_uint(f1);
    r1 += 0x7fffu + ((r1 >> 16) & 1u);
    return __builtin_amdgcn_perm(r1, r0, 0x07060302u);
}

union FragU { bf16x8 v; unsigned u[4]; };

// Round-11 insight: VALUBusy is a per-CU average over 4 SIMDs -> r11's lone
// wave ran its SIMD ~67% VALU-busy: 16 tanh = 32 quarter-rate transcendentals
// (~256 issue-cyc) concentrated on one issue port. The 4-wave N-split
// amortizes that 4x (r9 beat r11 despite its barriers). This round combines
// r9's structure with r11's chain cuts:
//  - state hi-plane-only (RNE bf16): per wave/step 2 ds_read_b128 + ONE
//    ds_write_b64 (the 4 packed hv are contiguous in the swizzled layout).
//  - hh MFMA depth 2 + parallel weight-lo correction.
//  - G reads issued immediately after the barrier; next step's off-path
//    x-pack + ih-MFMAs cover the read latency.
// Layouts (verified r5-r11): C/D row(m)=4qd+r, col(n)=ln. A: m=ln, k=8qd+j.
//   B: n=ln, k=8qd+j (+32kt). A=W rows (u=16nt+ln), B=state G[k=u][n=batch].
// G in LDS (u16): buf*1024 + kt*512 + ln*32 + slot*8 + j, slot=(qd+(ln>>1))&3.
__global__ __launch_bounds__(256, 1) void rnn_ns2_kernel(
    const float* __restrict__ x,     // [B, T, 32]
    const float* __restrict__ W_ih,  // [64, 32]
    const float* __restrict__ W_hh,  // [64, 64]
    const float* __restrict__ b_ih,  // [64]
    const float* __restrict__ b_hh,  // [64]
    const float* __restrict__ W_fc,  // [1, 64]
    const float* __restrict__ b_fc,  // [1]
    float* __restrict__ out)         // [B, 1]
{
    const int tid  = threadIdx.x;
    const int nt   = tid >> 6;        // wave id: owns hidden rows [16nt, 16nt+16)
    const int lane = tid & 63;
    const int ln   = lane & 15;
    const int qd   = lane >> 4;
    const int b0   = blockIdx.x * 16;

    __shared__ __align__(16) unsigned short Gs[2048];  // 4 KB: 2 bufs, hi plane
    __shared__ float Ps[64];

    { // zero buffer 0 (h_{-1} = 0)
        unsigned* z = (unsigned*)Gs;
        for (int i = tid; i < 512; i += 256) z[i] = 0u;
    }

    // ---- Static A-operand weights for THIS wave's u-tile ----
    const int mrow = nt * 16 + ln;
    bf16x8 WihH, WihL, WhhH[2], WhhL[2];
    {
        float f[8];
        const float* ri = W_ih + mrow * INPUT + qd * 8;
        *(float4*)&f[0] = *(const float4*)ri;
        *(float4*)&f[4] = *(const float4*)(ri + 4);
        split8(f, WihH, WihL);
        const float* rh = W_hh + mrow * HIDDEN + qd * 8;
#pragma unroll
        for (int kt = 0; kt < 2; ++kt) {
            *(float4*)&f[0] = *(const float4*)(rh + kt * 32);
            *(float4*)&f[4] = *(const float4*)(rh + kt * 32 + 4);
            split8(f, WhhH[kt], WhhL[kt]);
        }
    }
    const int u0 = nt * 16 + qd * 4;   // this lane's 4 output rows
    floatx4 bbv, wfcv;
    {
        float4 bi = *(const float4*)(b_ih + u0);
        float4 bh = *(const float4*)(b_hh + u0);
        bbv[0] = bi.x + bh.x; bbv[1] = bi.y + bh.y;
        bbv[2] = bi.z + bh.z; bbv[3] = bi.w + bh.w;
        float4 wf = *(const float4*)(W_fc + u0);
        wfcv[0] = wf.x; wfcv[1] = wf.y; wfcv[2] = wf.z; wfcv[3] = wf.w;
    }

    // Reader base (B-frag) and writer base (this lane's 4 contiguous u).
    const int rbase = ln * 32 + ((qd + (ln >> 1)) & 3) * 8;
    const int wbase = (u0 >> 5) * 512 + ln * 32 +
                      ((((u0 >> 3) & 3) + (ln >> 1)) & 3) * 8 + (u0 & 7);

    const float* xp = x + (size_t)(b0 + ln) * (SEQ * INPUT) + qd * 8;

    // 4-slot circular x prefetch (slot s holds x[t], t === s mod 4).
    float4 xa[4], xb[4];
#pragma unroll
    for (int i = 0; i < 4; ++i) {
        xa[i] = *(const float4*)(xp + i * INPUT);
        xb[i] = *(const float4*)(xp + i * INPUT + 4);
    }

    // ih-projection for t=0.
    floatx4 ihacc;
    {
        FragU xH, xL;
        packpair(xa[0].x, xa[0].y, xH.u[0], xL.u[0]);
        packpair(xa[0].z, xa[0].w, xH.u[1], xL.u[1]);
        packpair(xb[0].x, xb[0].y, xH.u[2], xL.u[2]);
        packpair(xb[0].z, xb[0].w, xH.u[3], xL.u[3]);
        ihacc = MFMA(WihH, xH.v, bbv);
        ihacc = MFMA(WihH, xL.v, ihacc);
        ihacc = MFMA(WihL, xH.v, ihacc);
    }

    __syncthreads();   // zero-init visible

    // Preload G frags for t=0 (buffer 0).
    bf16x8 g0 = *(const bf16x8*)(Gs + rbase);
    bf16x8 g1 = *(const bf16x8*)(Gs + rbase + 512);

    float hv[4];

#pragma unroll 1
    for (int tb = 0; tb < SEQ; tb += 4) {
#pragma unroll
        for (int s = 0; s < 4; ++s) {
            const int t = tb + s;
            // Refill slot s with x[t+4] (3 steps of slack before use).
            const int tn = (t + 4 < SEQ) ? t + 4 : SEQ - 1;
            xa[s] = *(const float4*)(xp + tn * INPUT);
            xb[s] = *(const float4*)(xp + tn * INPUT + 4);

            // Off-path: ih-projection for t+1 (covers the g read latency).
            const float4 na = xa[(s + 1) & 3], nb = xb[(s + 1) & 3];
            FragU nxH, nxL;
            packpair(na.x, na.y, nxH.u[0], nxL.u[0]);
            packpair(na.z, na.w, nxH.u[1], nxL.u[1]);
            packpair(nb.x, nb.y, nxH.u[2], nxL.u[2]);
            packpair(nb.z, nb.w, nxH.u[3], nxL.u[3]);
            floatx4 ihn = MFMA(WihH, nxH.v, bbv);
            ihn = MFMA(WihH, nxL.v, ihn);
            ihn = MFMA(WihL, nxH.v, ihn);

            // hh critical path: depth-2 main + parallel depth-2 lo-correction.
            floatx4 a = MFMA(WhhH[0], g0, ihacc);
            a = MFMA(WhhH[1], g1, a);
            floatx4 c = {0.f, 0.f, 0.f, 0.f};
            c = MFMA(WhhL[0], g0, c);
            c = MFMA(WhhL[1], g1, c);

            // tanh of this wave's 4 elements (only ~8 transcendentals/wave).
#pragma unroll
            for (int r = 0; r < 4; ++r) {
                float p = a[r] + c[r];
                float e = __expf(2.0f * p);
                hv[r] = 1.0f - 2.0f * __builtin_amdgcn_rcpf(e + 1.0f);
            }

            // Pack 4 -> 2 u32, ONE ds_write_b64 into the other buffer.
            unsigned w0 = pack_rne(hv[0], hv[1]);
            unsigned w1 = pack_rne(hv[2], hv[3]);
            uint2 wv; wv.x = w0; wv.y = w1;
            *(uint2*)(Gs + (((t & 1) ^ 1) << 10) + wbase) = wv;

            LDS_BARRIER();   // LDS-only drain; x loads stay in flight.

            // Read G for t+1 immediately (latency covered by next off-path).
            const unsigned short* Hr = Gs + (((t & 1) ^ 1) << 10) + rbase;
            g0 = *(const bf16x8*)(Hr);
            g1 = *(const bf16x8*)(Hr + 512);

            ihacc = ihn;
        }
    }

    // ---- Head: out[b] = sum_u wfc[u] * h[u][b] + b_fc ----
    float acc = wfcv[0] * hv[0] + wfcv[1] * hv[1] + wfcv[2] * hv[2] + wfcv[3] * hv[3];
    acc += __shfl_xor(acc, 16, 64);
    acc += __shfl_xor(acc, 32, 64);
    if (qd == 0) Ps[nt * 16 + ln] = acc;
    __syncthreads();
    if (tid < 16)
        out[b0 + tid] = Ps[tid] + Ps[16 + tid] + Ps[32 + tid] + Ps[48 + tid] + b_fc[0];
}

extern "C" void kernel_launch(void* const* d_in, const int* in_sizes, int n_in,
                              void* d_out, int out_size, void* d_ws, size_t ws_size,
                              hipStream_t stream) {
    const float* x    = (const float*)d_in[0];
    const float* W_ih = (const float*)d_in[1];
    const float* W_hh = (const float*)d_in[2];
    const float* b_ih = (const float*)d_in[3];
    const float* b_hh = (const float*)d_in[4];
    const float* W_fc = (const float*)d_in[5];
    const float* b_fc = (const float*)d_in[6];
    float* out = (float*)d_out;

    // 256 tiles of 16 chains; 4 waves/block (one per SIMD), 1 block per CU.
    rnn_ns2_kernel<<<dim3(BATCH / 16), dim3(256), 0, stream>>>(
        x, W_ih, W_hh, b_ih, b_hh, W_fc, b_fc, out);
}